// Round 6
// baseline (8384.998 us; speedup 1.0000x reference)
//
#include <hip/hip_runtime.h>
#include <math.h>
#include <cstdio>

// ---------------------------------------------------------------------------
// FNO2d forward, MI355X. Channel-last f32 activations [B,H,W,C], B=4.
// Spectral conv via partial DFT. Round 6: float4 dual-operand inner loops
// (4 ch/iter), 16B-aligned LDS rows, folded upsample+DFT twiddles (g-table).
// ---------------------------------------------------------------------------

__device__ __forceinline__ float gelu_f(float v) {
    return 0.5f * v * (1.0f + erff(v * 0.70710678118654752f));
}

// tw[t] = (cos(2*pi*t/256), sin(2*pi*t/256))
__global__ __launch_bounds__(256) void init_tw_kernel(float2* tw) {
    int t = threadIdx.x;
    tw[t] = make_float2(cospif(t * (1.0f / 128.0f)), sinpif(t * (1.0f / 128.0f)));
}

// [Co,Ci] -> dst[i*Co + o]
__global__ __launch_bounds__(256) void transpose_mat_kernel(const float* __restrict__ src,
                                                            float* __restrict__ dst,
                                                            int Co, int Ci) {
    int idx = blockIdx.x * blockDim.x + threadIdx.x;
    if (idx >= Ci * Co) return;
    int o = idx % Co; int i = idx / Co;
    dst[idx] = src[(size_t)o * Ci + i];
}

// Stage A: Fx[(by*M2+kx)*Ctot + Coff + c] = sum_x u(b,y,x,c) * e^{-2pi i kx x/W}
// SRC: 0 direct [.,H,W,C]; 1 lift from x[.,H,W,6]; 2 bilinear-up from
// [.,Hs,Ws,C] with the x-upsample FOLDED into modified twiddles g[j][k]
// (y-upsample still via 2-row blend). Block = 4 rows x 64 channels.
template <int M2, int SRC, int W_T>
__global__ __launch_bounds__(256, 4) void dftx_kernel(
    const float* __restrict__ U, int C, int Coff, int Ctot,
    int H, int Hs, int Ws,
    const float* __restrict__ liftW, const float* __restrict__ liftB,
    int stepW, const float2* __restrict__ tw, float2* __restrict__ Fx) {
    constexpr int W = W_T;
    constexpr int WS2 = W_T / 2;
    __shared__ float2 twxk[(SRC == 2) ? (WS2 * M2) : (W * M2)];
    int tid = threadIdx.x;
    if constexpr (SRC == 2) {
        for (int t = tid; t < WS2 * M2; t += 256) {
            int j = t / M2, k = t - (t / M2) * M2;
            float wr = 0.f, wi = 0.f;
            auto addE = [&](int xx, float w) {
                float2 e = tw[(xx * k * stepW) & 255];
                wr += w * e.x; wi += w * e.y;
            };
            if (j == 0)            { addE(0, 1.0f); addE(1, 0.75f); addE(2, 0.25f); }
            else if (j == WS2 - 1) { addE(2 * j - 1, 0.25f); addE(2 * j, 0.75f); addE(2 * j + 1, 1.0f); }
            else                   { addE(2 * j - 1, 0.25f); addE(2 * j, 0.75f);
                                     addE(2 * j + 1, 0.75f); addE(2 * j + 2, 0.25f); }
            twxk[t] = make_float2(wr, wi);
        }
    } else {
        for (int t = tid; t < W * M2; t += 256) {
            int x = t / M2, k = t - (t / M2) * M2;
            twxk[t] = tw[(x * k * stepW) & 255];
        }
    }
    __syncthreads();
    int by = blockIdx.x * 4 + (tid >> 6);      // b*H + y
    int c = blockIdx.y * 64 + (tid & 63);
    if (c >= C) return;

    const float* rowD = nullptr;
    const float* Sa = nullptr; const float* Sb = nullptr;
    float wy = 0.f, bc = 0.f;
    float w6[6] = {0, 0, 0, 0, 0, 0};
    if constexpr (SRC == 0) {
        rowD = U + (size_t)by * W * C + c;
    } else if constexpr (SRC == 1) {
        bc = liftB[c];
#pragma unroll
        for (int j = 0; j < 6; j++) w6[j] = liftW[c * 6 + j];
    } else {
        int b = by / H, y = by % H;
        float fy = 0.5f * y - 0.25f;
        int y0 = (int)floorf(fy); wy = fy - y0;
        int ya = y0 < 0 ? 0 : y0;
        int yb = (y0 + 1 > Hs - 1) ? Hs - 1 : y0 + 1;
        Sa = U + ((size_t)(b * Hs + ya) * Ws) * C + c;
        Sb = U + ((size_t)(b * Hs + yb) * Ws) * C + c;
    }

    float ar[M2], ai[M2];
#pragma unroll
    for (int k = 0; k < M2; k++) { ar[k] = 0.f; ai[k] = 0.f; }
    if constexpr (SRC == 2) {
        for (int js = 0; js < WS2; js++) {
            float sa = Sa[(size_t)js * C], sb = Sb[(size_t)js * C];
            float u = sa * (1.f - wy) + sb * wy;
            const float4* gp = (const float4*)&twxk[js * M2];
#pragma unroll
            for (int k2 = 0; k2 < M2 / 2; k2++) {
                float4 g4 = gp[k2];
                ar[2 * k2] += u * g4.x;     ai[2 * k2] -= u * g4.y;
                ar[2 * k2 + 1] += u * g4.z; ai[2 * k2 + 1] -= u * g4.w;
            }
        }
    } else {
        for (int x = 0; x < W; x++) {
            float u;
            if constexpr (SRC == 0) {
                u = rowD[(size_t)x * C];
            } else {
                const float* xp = U + ((size_t)by * W + x) * 6;
                u = bc;
#pragma unroll
                for (int j = 0; j < 6; j++) u += w6[j] * xp[j];
            }
            const float4* wp = (const float4*)&twxk[x * M2];
#pragma unroll
            for (int k2 = 0; k2 < M2 / 2; k2++) {
                float4 t4 = wp[k2];
                ar[2 * k2] += u * t4.x;     ai[2 * k2] -= u * t4.y;
                ar[2 * k2 + 1] += u * t4.z; ai[2 * k2 + 1] -= u * t4.w;
            }
        }
    }
    float2* o = Fx + ((size_t)by * M2) * Ctot + Coff + c;
#pragma unroll
    for (int k = 0; k < M2; k++) o[(size_t)k * Ctot] = make_float2(ar[k], ai[k]);
}

// Stage B: XF[((b*2m1+kyi)*m2+kx)*Ct + c] = sum_y Fx[...] * e^{-2pi i ky y/H}
__global__ __launch_bounds__(256, 4) void dfty_kernel(
    const float2* __restrict__ Fx, int H, int m1, int m2, int Ct,
    int stepH, const float2* __restrict__ tw, float2* __restrict__ XF, int N) {
    __shared__ float twc[256], tws[256];
    for (int t = threadIdx.x; t < 256; t += blockDim.x) {
        float2 v = tw[t]; twc[t] = v.x; tws[t] = v.y;
    }
    __syncthreads();
    int idx = blockIdx.x * blockDim.x + threadIdx.x;
    if (idx >= N) return;
    int c = idx % Ct; int r = idx / Ct;
    int kx = r % m2;  r /= m2;
    int kyi = r % (2 * m1); int b = r / (2 * m1);
    int ky = (kyi < m1) ? kyi : (H - 2 * m1 + kyi);
    int tstep = (ky * stepH) & 255;
    const float2* base = Fx + ((size_t)(b * H) * m2 + kx) * Ct + c;
    size_t stride = (size_t)m2 * Ct;
    float accr = 0.f, acci = 0.f;
    int t = 0;
    for (int y = 0; y < H; y++) {
        float2 f = base[(size_t)y * stride];
        float cc = twc[t], ss = tws[t];
        accr += f.x * cc + f.y * ss;   // * e^{-i th}
        acci += f.y * cc - f.x * ss;
        t = (t + tstep) & 255;
    }
    XF[idx] = make_float2(accr, acci);
}

// Stage C: mode-mix, original weight layout [Ci,Co,m1,m2,2], 4 batches in regs.
__global__ __launch_bounds__(128, 2) void modemix2_kernel(
    const float2* __restrict__ XF,
    const float* __restrict__ w1f, const float* __restrict__ w2f,
    int Ci, int Co, int m1, int m2, float2* __restrict__ OF) {
    __shared__ float2 xsm[4][224];
    int mode = blockIdx.x;
    int nmode = 2 * m1 * m2;
    for (int t = threadIdx.x; t < 4 * Ci; t += blockDim.x) {
        int b = t / Ci, i = t - b * Ci;
        xsm[b][i] = XF[((size_t)b * nmode + mode) * Ci + i];
    }
    __syncthreads();
    int o = threadIdx.x;
    if (o >= Co) return;
    int kx = mode % m2; int kyi = mode / m2;
    const float2* w = (const float2*)((kyi < m1) ? w1f : w2f);
    int ky = (kyi < m1) ? kyi : (kyi - m1);
    float ar0 = 0, ai0 = 0, ar1 = 0, ai1 = 0, ar2 = 0, ai2 = 0, ar3 = 0, ai3 = 0;
    for (int i = 0; i < Ci; i++) {
        float2 wv = w[(((size_t)i * Co + o) * m1 + ky) * m2 + kx];
        float2 a = xsm[0][i], b2 = xsm[1][i], c2 = xsm[2][i], d2 = xsm[3][i];
        ar0 += a.x * wv.x - a.y * wv.y;  ai0 += a.x * wv.y + a.y * wv.x;
        ar1 += b2.x * wv.x - b2.y * wv.y; ai1 += b2.x * wv.y + b2.y * wv.x;
        ar2 += c2.x * wv.x - c2.y * wv.y; ai2 += c2.x * wv.y + c2.y * wv.x;
        ar3 += d2.x * wv.x - d2.y * wv.y; ai3 += d2.x * wv.y + d2.y * wv.x;
    }
    OF[((size_t)0 * nmode + mode) * Co + o] = make_float2(ar0, ai0);
    OF[((size_t)1 * nmode + mode) * Co + o] = make_float2(ar1, ai1);
    OF[((size_t)2 * nmode + mode) * Co + o] = make_float2(ar2, ai2);
    OF[((size_t)3 * nmode + mode) * Co + o] = make_float2(ar3, ai3);
}

// Stage D: Gy[((b*H+y)*m2+kx)*Co+o] = sum_kyi OF[...] * e^{+2pi i ky y/H}
__global__ __launch_bounds__(256, 4) void idfty_kernel(
    const float2* __restrict__ OF, int H, int m1, int m2, int Co,
    int stepH, const float2* __restrict__ tw, float2* __restrict__ Gy, int N) {
    __shared__ float twc[256], tws[256];
    for (int t = threadIdx.x; t < 256; t += blockDim.x) {
        float2 v = tw[t]; twc[t] = v.x; tws[t] = v.y;
    }
    __syncthreads();
    int idx = blockIdx.x * blockDim.x + threadIdx.x;
    if (idx >= N) return;
    int o = idx % Co; int r = idx / Co;
    int kx = r % m2;  r /= m2;
    int y = r % H;    int b = r / H;
    float accr = 0.f, acci = 0.f;
    for (int kyi = 0; kyi < 2 * m1; kyi++) {
        int ky = (kyi < m1) ? kyi : (H - 2 * m1 + kyi);
        int t = (ky * y * stepH) & 255;
        float2 f = OF[((size_t)(b * 2 * m1 + kyi) * m2 + kx) * Co + o];
        float cc = twc[t], ss = tws[t];
        accr += f.x * cc - f.y * ss;   // * e^{+i th}
        acci += f.x * ss + f.y * cc;
    }
    Gy[idx] = make_float2(accr, acci);
}

// Stage E: out = gelu( spec_synth + conv1x1([A|B]) + bias ), 4x4 reg tiling,
// 4 channels per inner iteration: 4 coalesced float4 weight loads +
// 4 broadcast ds_read_b128 + 64 FMA. Rows padded to 16B (CIP = CIMAX+4).
template <int SRCA, bool HASB, int CO, int PG, int CIMAX, int M2>
__global__ __launch_bounds__((CO / 4) * PG, 2) void synth_kernel(
    const float2* __restrict__ Gy,
    const float* __restrict__ A, int CA, int HsA, int WsA,
    const float* __restrict__ UB, int CB,
    const float* __restrict__ liftW, const float* __restrict__ liftB,
    const float* __restrict__ WcT, const float* __restrict__ bias,
    int H, int W, int stepW, float invHW,
    const float2* __restrict__ tw, float* __restrict__ out) {
    constexpr int OQ = CO / 4;
    constexpr int BLK = OQ * PG;
    constexpr int P = PG * 4;
    constexpr int CIP = CIMAX + 4;
    __shared__ float xs[P][CIP];
    __shared__ float2 twL[M2][P];
    int tid = threadIdx.x;
    int pix0 = blockIdx.x * P;
    int x0 = pix0 % W;  int by = pix0 / W;     // all P pixels share one row
    for (int t = tid; t < M2 * P; t += BLK) {
        int k = t / P, p = t - (t / P) * P;
        float2 v = tw[((x0 + p) * k * stepW) & 255];
        float s = ((k == 0) ? 1.f : 2.f) * invHW;
        twL[k][p] = make_float2(s * v.x, s * v.y);
    }
    const int Ci = CA + (HASB ? CB : 0);
    for (int t = tid; t < P * Ci; t += BLK) {
        int p = t / Ci, i = t - p * Ci;
        int pix = pix0 + p;
        float val;
        if (HASB && i >= CA) {
            val = UB[(size_t)pix * CB + (i - CA)];
        } else if constexpr (SRCA == 0) {
            val = A[(size_t)pix * CA + i];
        } else if constexpr (SRCA == 1) {
            const float* xp = A + (size_t)pix * 6;
            float a = liftB[i];
#pragma unroll
            for (int j = 0; j < 6; j++) a += xp[j] * liftW[i * 6 + j];
            val = a;
        } else {
            int xx = pix % W; int r = pix / W; int y = r % H; int b = r / H;
            float fy = 0.5f * y - 0.25f, fx = 0.5f * xx - 0.25f;
            int y0 = (int)floorf(fy); float wy = fy - y0;
            int x0i = (int)floorf(fx); float wx = fx - x0i;
            int ya = y0 < 0 ? 0 : y0;
            int yb = (y0 + 1 > HsA - 1) ? HsA - 1 : y0 + 1;
            int xa = x0i < 0 ? 0 : x0i;
            int xb2 = (x0i + 1 > WsA - 1) ? WsA - 1 : x0i + 1;
            const float* base = A + ((size_t)b * HsA * WsA) * CA + i;
            float v00 = base[((size_t)ya * WsA + xa) * CA];
            float v01 = base[((size_t)ya * WsA + xb2) * CA];
            float v10 = base[((size_t)yb * WsA + xa) * CA];
            float v11 = base[((size_t)yb * WsA + xb2) * CA];
            val = (1.f - wy) * ((1.f - wx) * v00 + wx * v01) +
                  wy * ((1.f - wx) * v10 + wx * v11);
        }
        xs[p][i] = val;
    }
    __syncthreads();
    int oq = tid % OQ, pg = tid / OQ;
    float acc[4][4];
#pragma unroll
    for (int q = 0; q < 4; q++)
#pragma unroll
        for (int j = 0; j < 4; j++) acc[q][j] = 0.f;
    // spectral x-synthesis (scale folded into twL)
    const float2* grow = Gy + ((size_t)by * M2) * CO + oq * 4;
    for (int k = 0; k < M2; k++) {
        float4 ga = *(const float4*)&grow[(size_t)k * CO];
        float4 gb = *(const float4*)&grow[(size_t)k * CO + 2];
#pragma unroll
        for (int q = 0; q < 4; q++) {
            float2 tq = twL[k][pg * 4 + q];
            acc[q][0] += ga.x * tq.x - ga.y * tq.y;
            acc[q][1] += ga.z * tq.x - ga.w * tq.y;
            acc[q][2] += gb.x * tq.x - gb.y * tq.y;
            acc[q][3] += gb.z * tq.x - gb.w * tq.y;
        }
    }
    // conv1x1: 4 channels per iteration
    const float* wbase = WcT + oq * 4;
    const int nch = Ci >> 2;
    for (int i4 = 0; i4 < nch; i4++) {
        float4 w0 = *(const float4*)&wbase[(size_t)(4 * i4 + 0) * CO];
        float4 w1 = *(const float4*)&wbase[(size_t)(4 * i4 + 1) * CO];
        float4 w2 = *(const float4*)&wbase[(size_t)(4 * i4 + 2) * CO];
        float4 w3 = *(const float4*)&wbase[(size_t)(4 * i4 + 3) * CO];
#pragma unroll
        for (int q = 0; q < 4; q++) {
            float4 a = *(const float4*)&xs[pg * 4 + q][i4 * 4];
            acc[q][0] += a.x * w0.x + a.y * w1.x + a.z * w2.x + a.w * w3.x;
            acc[q][1] += a.x * w0.y + a.y * w1.y + a.z * w2.y + a.w * w3.y;
            acc[q][2] += a.x * w0.z + a.y * w1.z + a.z * w2.z + a.w * w3.z;
            acc[q][3] += a.x * w0.w + a.y * w1.w + a.z * w2.w + a.w * w3.w;
        }
    }
    float4 bb = *(const float4*)&bias[oq * 4];
#pragma unroll
    for (int q = 0; q < 4; q++) {
        int pix = pix0 + pg * 4 + q;
        float4 r;
        r.x = gelu_f(acc[q][0] + bb.x);
        r.y = gelu_f(acc[q][1] + bb.y);
        r.z = gelu_f(acc[q][2] + bb.z);
        r.w = gelu_f(acc[q][3] + bb.w);
        *(float4*)&out[(size_t)pix * CO + oq * 4] = r;
    }
}

// Head: out3 = fc2( gelu( fc1(x) ) ). Block 256 = 64 jq x 4 pg, P=16 px.
__global__ __launch_bounds__(256, 2) void head_kernel(
    const float* __restrict__ xin, const float* __restrict__ fc1t,
    const float* __restrict__ fc1b, const float* __restrict__ fc2w,
    const float* __restrict__ fc2b, float* __restrict__ out) {
    __shared__ float xs[16][68];
    __shared__ float red[64][49];
    int tid = threadIdx.x;
    int pix0 = blockIdx.x * 16;
    const float* src = xin + (size_t)pix0 * 64;
    for (int t = tid; t < 16 * 64; t += 256) xs[t >> 6][t & 63] = src[t];
    __syncthreads();
    int jq = tid & 63, pg = tid >> 6;
    float acc[4][4];
#pragma unroll
    for (int q = 0; q < 4; q++)
#pragma unroll
        for (int j = 0; j < 4; j++) acc[q][j] = 0.f;
    const float* wrow = fc1t + jq * 4;
    for (int i4 = 0; i4 < 16; i4++) {
        float4 w0 = *(const float4*)&wrow[(size_t)(4 * i4 + 0) * 256];
        float4 w1 = *(const float4*)&wrow[(size_t)(4 * i4 + 1) * 256];
        float4 w2 = *(const float4*)&wrow[(size_t)(4 * i4 + 2) * 256];
        float4 w3 = *(const float4*)&wrow[(size_t)(4 * i4 + 3) * 256];
#pragma unroll
        for (int q = 0; q < 4; q++) {
            float4 a = *(const float4*)&xs[pg * 4 + q][i4 * 4];
            acc[q][0] += a.x * w0.x + a.y * w1.x + a.z * w2.x + a.w * w3.x;
            acc[q][1] += a.x * w0.y + a.y * w1.y + a.z * w2.y + a.w * w3.y;
            acc[q][2] += a.x * w0.z + a.y * w1.z + a.z * w2.z + a.w * w3.z;
            acc[q][3] += a.x * w0.w + a.y * w1.w + a.z * w2.w + a.w * w3.w;
        }
    }
    float4 b1 = *(const float4*)&fc1b[jq * 4];
    float4 w20 = *(const float4*)&fc2w[0 * 256 + jq * 4];
    float4 w21 = *(const float4*)&fc2w[1 * 256 + jq * 4];
    float4 w22 = *(const float4*)&fc2w[2 * 256 + jq * 4];
#pragma unroll
    for (int q = 0; q < 4; q++) {
        float h0 = gelu_f(acc[q][0] + b1.x);
        float h1 = gelu_f(acc[q][1] + b1.y);
        float h2 = gelu_f(acc[q][2] + b1.z);
        float h3 = gelu_f(acc[q][3] + b1.w);
        int col = (pg * 4 + q) * 3;
        red[jq][col + 0] = h0 * w20.x + h1 * w20.y + h2 * w20.z + h3 * w20.w;
        red[jq][col + 1] = h0 * w21.x + h1 * w21.y + h2 * w21.z + h3 * w21.w;
        red[jq][col + 2] = h0 * w22.x + h1 * w22.y + h2 * w22.z + h3 * w22.w;
    }
    __syncthreads();
    if (tid < 48) {
        float s = 0.f;
        for (int j = 0; j < 64; j++) s += red[j][tid];
        int px = tid / 3, o3 = tid - 3 * px;
        out[(size_t)(pix0 + px) * 3 + o3] = s + fc2b[o3];
    }
}

// 2x2 mean pool; out dims [B,H2,W2,C]
__global__ __launch_bounds__(256, 4) void pool_kernel(
    const float* __restrict__ in, float* __restrict__ out,
    int H2, int W2, int C, int N) {
    int idx = blockIdx.x * blockDim.x + threadIdx.x;
    if (idx >= N) return;
    int c = idx % C; int r = idx / C;
    int xo = r % W2; r /= W2;
    int yo = r % H2; int b = r / H2;
    int W = W2 * 2;
    const float* p = in + (((size_t)(b * (H2 * 2) + 2 * yo) * W) + 2 * xo) * C + c;
    float v = p[0] + p[C] + p[(size_t)W * C] + p[(size_t)W * C + C];
    out[idx] = 0.25f * v;
}

// ---------------------------------------------------------------------------

static inline unsigned nb_(size_t n, int b) { return (unsigned)((n + b - 1) / b); }

extern "C" void kernel_launch(void* const* d_in, const int* in_sizes, int n_in,
                              void* d_out, int out_size, void* d_ws, size_t ws_size,
                              hipStream_t stream) {
    (void)in_sizes; (void)n_in; (void)out_size;
    const float* x      = (const float*)d_in[0];
    const float* fcin_w = (const float*)d_in[1];
    const float* fcin_b = (const float*)d_in[2];
    const float* sc1_w1 = (const float*)d_in[3];
    const float* sc1_w2 = (const float*)d_in[4];
    const float* c1_w   = (const float*)d_in[5];
    const float* c1_b   = (const float*)d_in[6];
    const float* sc2_w1 = (const float*)d_in[7];
    const float* sc2_w2 = (const float*)d_in[8];
    const float* c2_w   = (const float*)d_in[9];
    const float* c2_b   = (const float*)d_in[10];
    const float* scb_w1 = (const float*)d_in[11];
    const float* scb_w2 = (const float*)d_in[12];
    const float* cb_w   = (const float*)d_in[13];
    const float* cb_b   = (const float*)d_in[14];
    const float* su2_w1 = (const float*)d_in[15];
    const float* su2_w2 = (const float*)d_in[16];
    const float* u2_w   = (const float*)d_in[17];
    const float* u2_b   = (const float*)d_in[18];
    const float* su1_w1 = (const float*)d_in[19];
    const float* su1_w2 = (const float*)d_in[20];
    const float* u1_w   = (const float*)d_in[21];
    const float* u1_b   = (const float*)d_in[22];
    const float* fc1_w  = (const float*)d_in[23];
    const float* fc1_b  = (const float*)d_in[24];
    const float* fc2_w  = (const float*)d_in[25];
    const float* fc2_b  = (const float*)d_in[26];
    float* out = (float*)d_out;

    float* wsf = (float*)d_ws;
    size_t off = 0;
    auto alloc = [&](size_t nfloats) -> float* {
        float* p = wsf + off;
        off += (nfloats + 63) & ~(size_t)63;
        return p;
    };

    float2* tw = (float2*)alloc(512);
    float* c1t  = alloc(64 * 64);
    float* c2t  = alloc(64 * 96);
    float* cbt  = alloc(96 * 128);
    float* u2t  = alloc(224 * 96);
    float* u1t  = alloc(160 * 64);
    float* fc1t = alloc(64 * 256);

    float* x1  = alloc((size_t)4 * 256 * 256 * 64);   // also x1o (in-place U1 out)
    float* x1d = alloc((size_t)4 * 128 * 128 * 64);   // reused as x2d
    float* x2  = alloc((size_t)4 * 128 * 128 * 96);
    float* xb  = alloc((size_t)4 * 64 * 64 * 128);
    float* x2o = alloc((size_t)4 * 128 * 128 * 96);

    float2* Fx = (float2*)alloc((size_t)2 * 4 * 256 * 12 * 160);
    float2* XF = (float2*)alloc((size_t)2 * 4 * 24 * 12 * 160);
    float2* OF = (float2*)alloc((size_t)2 * 4 * 24 * 12 * 128);
    float2* Gy = (float2*)alloc((size_t)2 * 4 * 256 * 12 * 96);

    size_t need = off * sizeof(float);
    if (ws_size < need) {
        fprintf(stderr, "[FNO2d] workspace too small: need %zu bytes, have %zu\n",
                need, ws_size);
        return;
    }
    float* x2d = x1d;

    init_tw_kernel<<<1, 256, 0, stream>>>(tw);
    transpose_mat_kernel<<<nb_(64 * 64, 256), 256, 0, stream>>>(c1_w, c1t, 64, 64);
    transpose_mat_kernel<<<nb_(64 * 96, 256), 256, 0, stream>>>(c2_w, c2t, 96, 64);
    transpose_mat_kernel<<<nb_(96 * 128, 256), 256, 0, stream>>>(cb_w, cbt, 128, 96);
    transpose_mat_kernel<<<nb_(224 * 96, 256), 256, 0, stream>>>(u2_w, u2t, 96, 224);
    transpose_mat_kernel<<<nb_(160 * 64, 256), 256, 0, stream>>>(u1_w, u1t, 64, 160);
    transpose_mat_kernel<<<nb_(64 * 256, 256), 256, 0, stream>>>(fc1_w, fc1t, 256, 64);

    int N;

    // ---- L1: lift(x) -> 64ch, 256x256, m=12, Co=64 -> x1
    dftx_kernel<12, 1, 256><<<dim3(256, 1), 256, 0, stream>>>(
        x, 64, 0, 64, 256, 0, 0, fcin_w, fcin_b, 1, tw, Fx);
    N = 4 * 24 * 12 * 64;
    dfty_kernel<<<nb_(N, 256), 256, 0, stream>>>(Fx, 256, 12, 12, 64, 1, tw, XF, N);
    modemix2_kernel<<<288, 128, 0, stream>>>(XF, sc1_w1, sc1_w2, 64, 64, 12, 12, OF);
    N = 4 * 256 * 12 * 64;
    idfty_kernel<<<nb_(N, 256), 256, 0, stream>>>(OF, 256, 12, 12, 64, 1, tw, Gy, N);
    synth_kernel<1, false, 64, 16, 64, 12><<<4 * 256 * 256 / 64, 256, 0, stream>>>(
        Gy, x, 64, 0, 0, nullptr, 0, fcin_w, fcin_b, c1t, c1_b,
        256, 256, 1, 1.0f / 65536.0f, tw, x1);
    N = 4 * 128 * 128 * 64;
    pool_kernel<<<nb_(N, 256), 256, 0, stream>>>(x1, x1d, 128, 128, 64, N);

    // ---- L2: x1d 64ch, 128x128, m=8, Co=96 -> x2
    dftx_kernel<8, 0, 128><<<dim3(128, 1), 256, 0, stream>>>(
        x1d, 64, 0, 64, 128, 0, 0, nullptr, nullptr, 2, tw, Fx);
    N = 4 * 16 * 8 * 64;
    dfty_kernel<<<nb_(N, 256), 256, 0, stream>>>(Fx, 128, 8, 8, 64, 2, tw, XF, N);
    modemix2_kernel<<<128, 128, 0, stream>>>(XF, sc2_w1, sc2_w2, 64, 96, 8, 8, OF);
    N = 4 * 128 * 8 * 96;
    idfty_kernel<<<nb_(N, 256), 256, 0, stream>>>(OF, 128, 8, 8, 96, 2, tw, Gy, N);
    synth_kernel<0, false, 96, 8, 64, 8><<<4 * 128 * 128 / 32, 192, 0, stream>>>(
        Gy, x1d, 64, 0, 0, nullptr, 0, nullptr, nullptr, c2t, c2_b,
        128, 128, 2, 1.0f / 16384.0f, tw, x2);
    N = 4 * 64 * 64 * 96;
    pool_kernel<<<nb_(N, 256), 256, 0, stream>>>(x2, x2d, 64, 64, 96, N);

    // ---- bottleneck: x2d 96ch, 64x64, m=4, Co=128 -> xb
    dftx_kernel<4, 0, 64><<<dim3(64, 2), 256, 0, stream>>>(
        x2d, 96, 0, 96, 64, 0, 0, nullptr, nullptr, 4, tw, Fx);
    N = 4 * 8 * 4 * 96;
    dfty_kernel<<<nb_(N, 256), 256, 0, stream>>>(Fx, 64, 4, 4, 96, 4, tw, XF, N);
    modemix2_kernel<<<32, 128, 0, stream>>>(XF, scb_w1, scb_w2, 96, 128, 4, 4, OF);
    N = 4 * 64 * 4 * 128;
    idfty_kernel<<<nb_(N, 256), 256, 0, stream>>>(OF, 64, 4, 4, 128, 4, tw, Gy, N);
    synth_kernel<0, false, 128, 8, 96, 4><<<4 * 64 * 64 / 32, 256, 0, stream>>>(
        Gy, x2d, 96, 0, 0, nullptr, 0, nullptr, nullptr, cbt, cb_b,
        64, 64, 4, 1.0f / 4096.0f, tw, xb);

    // ---- U2: [up(xb) 128ch | x2 96ch], 128x128, m=8, Co=96 -> x2o
    dftx_kernel<8, 2, 128><<<dim3(128, 2), 256, 0, stream>>>(
        xb, 128, 0, 224, 128, 64, 64, nullptr, nullptr, 2, tw, Fx);
    dftx_kernel<8, 0, 128><<<dim3(128, 2), 256, 0, stream>>>(
        x2, 96, 128, 224, 128, 0, 0, nullptr, nullptr, 2, tw, Fx);
    N = 4 * 16 * 8 * 224;
    dfty_kernel<<<nb_(N, 256), 256, 0, stream>>>(Fx, 128, 8, 8, 224, 2, tw, XF, N);
    modemix2_kernel<<<128, 128, 0, stream>>>(XF, su2_w1, su2_w2, 224, 96, 8, 8, OF);
    N = 4 * 128 * 8 * 96;
    idfty_kernel<<<nb_(N, 256), 256, 0, stream>>>(OF, 128, 8, 8, 96, 2, tw, Gy, N);
    synth_kernel<2, true, 96, 8, 224, 8><<<4 * 128 * 128 / 32, 192, 0, stream>>>(
        Gy, xb, 128, 64, 64, x2, 96, nullptr, nullptr, u2t, u2_b,
        128, 128, 2, 1.0f / 16384.0f, tw, x2o);

    // ---- U1: [up(x2o) 96ch | x1 64ch], 256x256, m=12, Co=64 -> x1 (in-place)
    dftx_kernel<12, 2, 256><<<dim3(256, 2), 256, 0, stream>>>(
        x2o, 96, 0, 160, 256, 128, 128, nullptr, nullptr, 1, tw, Fx);
    dftx_kernel<12, 0, 256><<<dim3(256, 1), 256, 0, stream>>>(
        x1, 64, 96, 160, 256, 0, 0, nullptr, nullptr, 1, tw, Fx);
    N = 4 * 24 * 12 * 160;
    dfty_kernel<<<nb_(N, 256), 256, 0, stream>>>(Fx, 256, 12, 12, 160, 1, tw, XF, N);
    modemix2_kernel<<<288, 128, 0, stream>>>(XF, su1_w1, su1_w2, 160, 64, 12, 12, OF);
    N = 4 * 256 * 12 * 64;
    idfty_kernel<<<nb_(N, 256), 256, 0, stream>>>(OF, 256, 12, 12, 64, 1, tw, Gy, N);
    // writes x1 in place: each block reads/writes only its own pixel rows of x1
    synth_kernel<2, true, 64, 16, 160, 12><<<4 * 256 * 256 / 64, 256, 0, stream>>>(
        Gy, x2o, 96, 128, 128, x1, 64, nullptr, nullptr, u1t, u1_b,
        256, 256, 1, 1.0f / 65536.0f, tw, x1);

    // ---- head: fc2(gelu(fc1(x1o)))
    head_kernel<<<4 * 256 * 256 / 16, 256, 0, stream>>>(
        x1, fc1t, fc1_b, fc2_w, fc2_b, out);
}

// Round 7
// 1670.906 us; speedup vs baseline: 5.0182x; 5.0182x over previous
//
#include <hip/hip_runtime.h>
#include <math.h>
#include <cstdio>

// ---------------------------------------------------------------------------
// FNO2d forward, MI355X. Channel-last f32 activations [B,H,W,C], B=4.
// Spectral conv via partial DFT. Round 7: r5-form inner loops (1 ch/iter,
// serialized weight stream — 4-load bursts caused 19.5GB HBM amplification),
// compile-time Ci, P=32 blocks for occupancy, folded upsample+DFT twiddles.
// ---------------------------------------------------------------------------

__device__ __forceinline__ float gelu_f(float v) {
    return 0.5f * v * (1.0f + erff(v * 0.70710678118654752f));
}

// tw[t] = (cos(2*pi*t/256), sin(2*pi*t/256))
__global__ __launch_bounds__(256) void init_tw_kernel(float2* tw) {
    int t = threadIdx.x;
    tw[t] = make_float2(cospif(t * (1.0f / 128.0f)), sinpif(t * (1.0f / 128.0f)));
}

// [Co,Ci] -> dst[i*Co + o]
__global__ __launch_bounds__(256) void transpose_mat_kernel(const float* __restrict__ src,
                                                            float* __restrict__ dst,
                                                            int Co, int Ci) {
    int idx = blockIdx.x * blockDim.x + threadIdx.x;
    if (idx >= Ci * Co) return;
    int o = idx % Co; int i = idx / Co;
    dst[idx] = src[(size_t)o * Ci + i];
}

// Stage A: Fx[(by*M2+kx)*Ctot + Coff + c] = sum_x u(b,y,x,c) * e^{-2pi i kx x/W}
// SRC: 0 direct; 1 lift from x[.,H,W,6]; 2 bilinear-up from [.,Hs,Ws,C] with
// the x-upsample folded into modified twiddles g[j][k].
template <int M2, int SRC, int W_T>
__global__ __launch_bounds__(256, 4) void dftx_kernel(
    const float* __restrict__ U, int C, int Coff, int Ctot,
    int H, int Hs, int Ws,
    const float* __restrict__ liftW, const float* __restrict__ liftB,
    int stepW, const float2* __restrict__ tw, float2* __restrict__ Fx) {
    constexpr int W = W_T;
    constexpr int WS2 = W_T / 2;
    __shared__ float2 twxk[(SRC == 2) ? (WS2 * M2) : (W * M2)];
    int tid = threadIdx.x;
    if constexpr (SRC == 2) {
        for (int t = tid; t < WS2 * M2; t += 256) {
            int j = t / M2, k = t - (t / M2) * M2;
            float wr = 0.f, wi = 0.f;
            auto addE = [&](int xx, float w) {
                float2 e = tw[(xx * k * stepW) & 255];
                wr += w * e.x; wi += w * e.y;
            };
            if (j == 0)            { addE(0, 1.0f); addE(1, 0.75f); addE(2, 0.25f); }
            else if (j == WS2 - 1) { addE(2 * j - 1, 0.25f); addE(2 * j, 0.75f); addE(2 * j + 1, 1.0f); }
            else                   { addE(2 * j - 1, 0.25f); addE(2 * j, 0.75f);
                                     addE(2 * j + 1, 0.75f); addE(2 * j + 2, 0.25f); }
            twxk[t] = make_float2(wr, wi);
        }
    } else {
        for (int t = tid; t < W * M2; t += 256) {
            int x = t / M2, k = t - (t / M2) * M2;
            twxk[t] = tw[(x * k * stepW) & 255];
        }
    }
    __syncthreads();
    int by = blockIdx.x * 4 + (tid >> 6);      // b*H + y
    int c = blockIdx.y * 64 + (tid & 63);
    if (c >= C) return;

    const float* rowD = nullptr;
    const float* Sa = nullptr; const float* Sb = nullptr;
    float wy = 0.f, bc = 0.f;
    float w6[6] = {0, 0, 0, 0, 0, 0};
    if constexpr (SRC == 0) {
        rowD = U + (size_t)by * W * C + c;
    } else if constexpr (SRC == 1) {
        bc = liftB[c];
#pragma unroll
        for (int j = 0; j < 6; j++) w6[j] = liftW[c * 6 + j];
    } else {
        int b = by / H, y = by % H;
        float fy = 0.5f * y - 0.25f;
        int y0 = (int)floorf(fy); wy = fy - y0;
        int ya = y0 < 0 ? 0 : y0;
        int yb = (y0 + 1 > Hs - 1) ? Hs - 1 : y0 + 1;
        Sa = U + ((size_t)(b * Hs + ya) * Ws) * C + c;
        Sb = U + ((size_t)(b * Hs + yb) * Ws) * C + c;
    }

    float ar[M2], ai[M2];
#pragma unroll
    for (int k = 0; k < M2; k++) { ar[k] = 0.f; ai[k] = 0.f; }
    if constexpr (SRC == 2) {
        for (int js = 0; js < WS2; js++) {
            float sa = Sa[(size_t)js * C], sb = Sb[(size_t)js * C];
            float u = sa * (1.f - wy) + sb * wy;
            const float4* gp = (const float4*)&twxk[js * M2];
#pragma unroll
            for (int k2 = 0; k2 < M2 / 2; k2++) {
                float4 g4 = gp[k2];
                ar[2 * k2] += u * g4.x;     ai[2 * k2] -= u * g4.y;
                ar[2 * k2 + 1] += u * g4.z; ai[2 * k2 + 1] -= u * g4.w;
            }
        }
    } else {
        for (int x = 0; x < W; x++) {
            float u;
            if constexpr (SRC == 0) {
                u = rowD[(size_t)x * C];
            } else {
                const float* xp = U + ((size_t)by * W + x) * 6;
                u = bc;
#pragma unroll
                for (int j = 0; j < 6; j++) u += w6[j] * xp[j];
            }
            const float4* wp = (const float4*)&twxk[x * M2];
#pragma unroll
            for (int k2 = 0; k2 < M2 / 2; k2++) {
                float4 t4 = wp[k2];
                ar[2 * k2] += u * t4.x;     ai[2 * k2] -= u * t4.y;
                ar[2 * k2 + 1] += u * t4.z; ai[2 * k2 + 1] -= u * t4.w;
            }
        }
    }
    float2* o = Fx + ((size_t)by * M2) * Ctot + Coff + c;
#pragma unroll
    for (int k = 0; k < M2; k++) o[(size_t)k * Ctot] = make_float2(ar[k], ai[k]);
}

// Stage B: XF[((b*2m1+kyi)*m2+kx)*Ct + c] = sum_y Fx[...] * e^{-2pi i ky y/H}
__global__ __launch_bounds__(256, 4) void dfty_kernel(
    const float2* __restrict__ Fx, int H, int m1, int m2, int Ct,
    int stepH, const float2* __restrict__ tw, float2* __restrict__ XF, int N) {
    __shared__ float twc[256], tws[256];
    for (int t = threadIdx.x; t < 256; t += blockDim.x) {
        float2 v = tw[t]; twc[t] = v.x; tws[t] = v.y;
    }
    __syncthreads();
    int idx = blockIdx.x * blockDim.x + threadIdx.x;
    if (idx >= N) return;
    int c = idx % Ct; int r = idx / Ct;
    int kx = r % m2;  r /= m2;
    int kyi = r % (2 * m1); int b = r / (2 * m1);
    int ky = (kyi < m1) ? kyi : (H - 2 * m1 + kyi);
    int tstep = (ky * stepH) & 255;
    const float2* base = Fx + ((size_t)(b * H) * m2 + kx) * Ct + c;
    size_t stride = (size_t)m2 * Ct;
    float accr = 0.f, acci = 0.f;
    int t = 0;
    for (int y = 0; y < H; y++) {
        float2 f = base[(size_t)y * stride];
        float cc = twc[t], ss = tws[t];
        accr += f.x * cc + f.y * ss;   // * e^{-i th}
        acci += f.y * cc - f.x * ss;
        t = (t + tstep) & 255;
    }
    XF[idx] = make_float2(accr, acci);
}

// Stage C: mode-mix, original weight layout [Ci,Co,m1,m2,2], 4 batches in regs.
__global__ __launch_bounds__(128, 2) void modemix2_kernel(
    const float2* __restrict__ XF,
    const float* __restrict__ w1f, const float* __restrict__ w2f,
    int Ci, int Co, int m1, int m2, float2* __restrict__ OF) {
    __shared__ float2 xsm[4][224];
    int mode = blockIdx.x;
    int nmode = 2 * m1 * m2;
    for (int t = threadIdx.x; t < 4 * Ci; t += blockDim.x) {
        int b = t / Ci, i = t - b * Ci;
        xsm[b][i] = XF[((size_t)b * nmode + mode) * Ci + i];
    }
    __syncthreads();
    int o = threadIdx.x;
    if (o >= Co) return;
    int kx = mode % m2; int kyi = mode / m2;
    const float2* w = (const float2*)((kyi < m1) ? w1f : w2f);
    int ky = (kyi < m1) ? kyi : (kyi - m1);
    float ar0 = 0, ai0 = 0, ar1 = 0, ai1 = 0, ar2 = 0, ai2 = 0, ar3 = 0, ai3 = 0;
    for (int i = 0; i < Ci; i++) {
        float2 wv = w[(((size_t)i * Co + o) * m1 + ky) * m2 + kx];
        float2 a = xsm[0][i], b2 = xsm[1][i], c2 = xsm[2][i], d2 = xsm[3][i];
        ar0 += a.x * wv.x - a.y * wv.y;  ai0 += a.x * wv.y + a.y * wv.x;
        ar1 += b2.x * wv.x - b2.y * wv.y; ai1 += b2.x * wv.y + b2.y * wv.x;
        ar2 += c2.x * wv.x - c2.y * wv.y; ai2 += c2.x * wv.y + c2.y * wv.x;
        ar3 += d2.x * wv.x - d2.y * wv.y; ai3 += d2.x * wv.y + d2.y * wv.x;
    }
    OF[((size_t)0 * nmode + mode) * Co + o] = make_float2(ar0, ai0);
    OF[((size_t)1 * nmode + mode) * Co + o] = make_float2(ar1, ai1);
    OF[((size_t)2 * nmode + mode) * Co + o] = make_float2(ar2, ai2);
    OF[((size_t)3 * nmode + mode) * Co + o] = make_float2(ar3, ai3);
}

// Stage D: Gy[((b*H+y)*m2+kx)*Co+o] = sum_kyi OF[...] * e^{+2pi i ky y/H}
__global__ __launch_bounds__(256, 4) void idfty_kernel(
    const float2* __restrict__ OF, int H, int m1, int m2, int Co,
    int stepH, const float2* __restrict__ tw, float2* __restrict__ Gy, int N) {
    __shared__ float twc[256], tws[256];
    for (int t = threadIdx.x; t < 256; t += blockDim.x) {
        float2 v = tw[t]; twc[t] = v.x; tws[t] = v.y;
    }
    __syncthreads();
    int idx = blockIdx.x * blockDim.x + threadIdx.x;
    if (idx >= N) return;
    int o = idx % Co; int r = idx / Co;
    int kx = r % m2;  r /= m2;
    int y = r % H;    int b = r / H;
    float accr = 0.f, acci = 0.f;
    for (int kyi = 0; kyi < 2 * m1; kyi++) {
        int ky = (kyi < m1) ? kyi : (H - 2 * m1 + kyi);
        int t = (ky * y * stepH) & 255;
        float2 f = OF[((size_t)(b * 2 * m1 + kyi) * m2 + kx) * Co + o];
        float cc = twc[t], ss = tws[t];
        accr += f.x * cc - f.y * ss;   // * e^{+i th}
        acci += f.x * ss + f.y * cc;
    }
    Gy[idx] = make_float2(accr, acci);
}

// Stage E: out = gelu( spec_synth + conv1x1([A|B]) + bias ), 4x4 reg tiling.
// P=32 pixels/block (one row slice), 1 weight float4 per inner iteration
// (serialized stream -> L2-hot; 4-load bursts caused HBM amplification).
// CI compile-time for software pipelining. LDS rows CI+1 (conflict-free).
template <int SRCA, bool HASB, int CO, int CI, int M2, int MINW>
__global__ __launch_bounds__((CO / 4) * 8, MINW) void synth_kernel(
    const float2* __restrict__ Gy,
    const float* __restrict__ A, int CA, int HsA, int WsA,
    const float* __restrict__ UB, int CB,
    const float* __restrict__ liftW, const float* __restrict__ liftB,
    const float* __restrict__ WcT, const float* __restrict__ bias,
    int H, int W, int stepW, float invHW,
    const float2* __restrict__ tw, float* __restrict__ out) {
    constexpr int OQ = CO / 4;
    constexpr int BLK = OQ * 8;
    constexpr int P = 32;
    constexpr int CIP = CI + 1;
    __shared__ float xs[P][CIP];
    __shared__ float2 twL[M2][P];
    int tid = threadIdx.x;
    int pix0 = blockIdx.x * P;
    int x0 = pix0 % W;  int by = pix0 / W;     // all P pixels share one row
    for (int t = tid; t < M2 * P; t += BLK) {
        int k = t / P, p = t - (t / P) * P;
        float2 v = tw[((x0 + p) * k * stepW) & 255];
        float s = ((k == 0) ? 1.f : 2.f) * invHW;
        twL[k][p] = make_float2(s * v.x, s * v.y);
    }
    for (int t = tid; t < P * CI; t += BLK) {
        int p = t / CI, i = t - p * CI;
        int pix = pix0 + p;
        float val;
        if (HASB && i >= CA) {
            val = UB[(size_t)pix * CB + (i - CA)];
        } else if constexpr (SRCA == 0) {
            val = A[(size_t)pix * CA + i];
        } else if constexpr (SRCA == 1) {
            const float* xp = A + (size_t)pix * 6;
            float a = liftB[i];
#pragma unroll
            for (int j = 0; j < 6; j++) a += xp[j] * liftW[i * 6 + j];
            val = a;
        } else {
            int xx = pix % W; int r = pix / W; int y = r % H; int b = r / H;
            float fy = 0.5f * y - 0.25f, fx = 0.5f * xx - 0.25f;
            int y0 = (int)floorf(fy); float wy = fy - y0;
            int x0i = (int)floorf(fx); float wx = fx - x0i;
            int ya = y0 < 0 ? 0 : y0;
            int yb = (y0 + 1 > HsA - 1) ? HsA - 1 : y0 + 1;
            int xa = x0i < 0 ? 0 : x0i;
            int xb2 = (x0i + 1 > WsA - 1) ? WsA - 1 : x0i + 1;
            const float* base = A + ((size_t)b * HsA * WsA) * CA + i;
            float v00 = base[((size_t)ya * WsA + xa) * CA];
            float v01 = base[((size_t)ya * WsA + xb2) * CA];
            float v10 = base[((size_t)yb * WsA + xa) * CA];
            float v11 = base[((size_t)yb * WsA + xb2) * CA];
            val = (1.f - wy) * ((1.f - wx) * v00 + wx * v01) +
                  wy * ((1.f - wx) * v10 + wx * v11);
        }
        xs[p][i] = val;
    }
    __syncthreads();
    int oq = tid % OQ, pg = tid / OQ;
    float acc[4][4];
#pragma unroll
    for (int q = 0; q < 4; q++)
#pragma unroll
        for (int j = 0; j < 4; j++) acc[q][j] = 0.f;
    // spectral x-synthesis (scale folded into twL)
    const float2* grow = Gy + ((size_t)by * M2) * CO + oq * 4;
#pragma unroll
    for (int k = 0; k < M2; k++) {
        float4 ga = *(const float4*)&grow[(size_t)k * CO];
        float4 gb = *(const float4*)&grow[(size_t)k * CO + 2];
#pragma unroll
        for (int q = 0; q < 4; q++) {
            float2 tq = twL[k][pg * 4 + q];
            acc[q][0] += ga.x * tq.x - ga.y * tq.y;
            acc[q][1] += ga.z * tq.x - ga.w * tq.y;
            acc[q][2] += gb.x * tq.x - gb.y * tq.y;
            acc[q][3] += gb.z * tq.x - gb.w * tq.y;
        }
    }
    // conv1x1: one coalesced float4 weight load per iteration
    const float* wrow = WcT + oq * 4;
#pragma unroll 8
    for (int i = 0; i < CI; i++) {
        float4 w = *(const float4*)&wrow[(size_t)i * CO];
#pragma unroll
        for (int q = 0; q < 4; q++) {
            float a = xs[pg * 4 + q][i];
            acc[q][0] += a * w.x; acc[q][1] += a * w.y;
            acc[q][2] += a * w.z; acc[q][3] += a * w.w;
        }
    }
    float4 bb = *(const float4*)&bias[oq * 4];
#pragma unroll
    for (int q = 0; q < 4; q++) {
        int pix = pix0 + pg * 4 + q;
        float4 r;
        r.x = gelu_f(acc[q][0] + bb.x);
        r.y = gelu_f(acc[q][1] + bb.y);
        r.z = gelu_f(acc[q][2] + bb.z);
        r.w = gelu_f(acc[q][3] + bb.w);
        *(float4*)&out[(size_t)pix * CO + oq * 4] = r;
    }
}

// Head: out3 = fc2( gelu( fc1(x) ) ). Block 256 = 64 jq x 4 pg, P=16 px.
// (r5-exact form: 1 weight float4 per iteration, scalar LDS reads.)
__global__ __launch_bounds__(256, 2) void head_kernel(
    const float* __restrict__ xin, const float* __restrict__ fc1t,
    const float* __restrict__ fc1b, const float* __restrict__ fc2w,
    const float* __restrict__ fc2b, float* __restrict__ out) {
    __shared__ float xs[16][65];
    __shared__ float red[64][49];
    int tid = threadIdx.x;
    int pix0 = blockIdx.x * 16;
    const float* src = xin + (size_t)pix0 * 64;
    for (int t = tid; t < 16 * 64; t += 256) xs[t >> 6][t & 63] = src[t];
    __syncthreads();
    int jq = tid & 63, pg = tid >> 6;
    float acc[4][4];
#pragma unroll
    for (int q = 0; q < 4; q++)
#pragma unroll
        for (int j = 0; j < 4; j++) acc[q][j] = 0.f;
    const float* wrow = fc1t + jq * 4;
    for (int i = 0; i < 64; i++) {
        float4 w = *(const float4*)&wrow[(size_t)i * 256];
#pragma unroll
        for (int q = 0; q < 4; q++) {
            float a = xs[pg * 4 + q][i];
            acc[q][0] += a * w.x; acc[q][1] += a * w.y;
            acc[q][2] += a * w.z; acc[q][3] += a * w.w;
        }
    }
    float4 b1 = *(const float4*)&fc1b[jq * 4];
    float4 w20 = *(const float4*)&fc2w[0 * 256 + jq * 4];
    float4 w21 = *(const float4*)&fc2w[1 * 256 + jq * 4];
    float4 w22 = *(const float4*)&fc2w[2 * 256 + jq * 4];
#pragma unroll
    for (int q = 0; q < 4; q++) {
        float h0 = gelu_f(acc[q][0] + b1.x);
        float h1 = gelu_f(acc[q][1] + b1.y);
        float h2 = gelu_f(acc[q][2] + b1.z);
        float h3 = gelu_f(acc[q][3] + b1.w);
        int col = (pg * 4 + q) * 3;
        red[jq][col + 0] = h0 * w20.x + h1 * w20.y + h2 * w20.z + h3 * w20.w;
        red[jq][col + 1] = h0 * w21.x + h1 * w21.y + h2 * w21.z + h3 * w21.w;
        red[jq][col + 2] = h0 * w22.x + h1 * w22.y + h2 * w22.z + h3 * w22.w;
    }
    __syncthreads();
    if (tid < 48) {
        float s = 0.f;
        for (int j = 0; j < 64; j++) s += red[j][tid];
        int px = tid / 3, o3 = tid - 3 * px;
        out[(size_t)(pix0 + px) * 3 + o3] = s + fc2b[o3];
    }
}

// 2x2 mean pool; out dims [B,H2,W2,C]
__global__ __launch_bounds__(256, 4) void pool_kernel(
    const float* __restrict__ in, float* __restrict__ out,
    int H2, int W2, int C, int N) {
    int idx = blockIdx.x * blockDim.x + threadIdx.x;
    if (idx >= N) return;
    int c = idx % C; int r = idx / C;
    int xo = r % W2; r /= W2;
    int yo = r % H2; int b = r / H2;
    int W = W2 * 2;
    const float* p = in + (((size_t)(b * (H2 * 2) + 2 * yo) * W) + 2 * xo) * C + c;
    float v = p[0] + p[C] + p[(size_t)W * C] + p[(size_t)W * C + C];
    out[idx] = 0.25f * v;
}

// ---------------------------------------------------------------------------

static inline unsigned nb_(size_t n, int b) { return (unsigned)((n + b - 1) / b); }

extern "C" void kernel_launch(void* const* d_in, const int* in_sizes, int n_in,
                              void* d_out, int out_size, void* d_ws, size_t ws_size,
                              hipStream_t stream) {
    (void)in_sizes; (void)n_in; (void)out_size;
    const float* x      = (const float*)d_in[0];
    const float* fcin_w = (const float*)d_in[1];
    const float* fcin_b = (const float*)d_in[2];
    const float* sc1_w1 = (const float*)d_in[3];
    const float* sc1_w2 = (const float*)d_in[4];
    const float* c1_w   = (const float*)d_in[5];
    const float* c1_b   = (const float*)d_in[6];
    const float* sc2_w1 = (const float*)d_in[7];
    const float* sc2_w2 = (const float*)d_in[8];
    const float* c2_w   = (const float*)d_in[9];
    const float* c2_b   = (const float*)d_in[10];
    const float* scb_w1 = (const float*)d_in[11];
    const float* scb_w2 = (const float*)d_in[12];
    const float* cb_w   = (const float*)d_in[13];
    const float* cb_b   = (const float*)d_in[14];
    const float* su2_w1 = (const float*)d_in[15];
    const float* su2_w2 = (const float*)d_in[16];
    const float* u2_w   = (const float*)d_in[17];
    const float* u2_b   = (const float*)d_in[18];
    const float* su1_w1 = (const float*)d_in[19];
    const float* su1_w2 = (const float*)d_in[20];
    const float* u1_w   = (const float*)d_in[21];
    const float* u1_b   = (const float*)d_in[22];
    const float* fc1_w  = (const float*)d_in[23];
    const float* fc1_b  = (const float*)d_in[24];
    const float* fc2_w  = (const float*)d_in[25];
    const float* fc2_b  = (const float*)d_in[26];
    float* out = (float*)d_out;

    float* wsf = (float*)d_ws;
    size_t off = 0;
    auto alloc = [&](size_t nfloats) -> float* {
        float* p = wsf + off;
        off += (nfloats + 63) & ~(size_t)63;
        return p;
    };

    float2* tw = (float2*)alloc(512);
    float* c1t  = alloc(64 * 64);
    float* c2t  = alloc(64 * 96);
    float* cbt  = alloc(96 * 128);
    float* u2t  = alloc(224 * 96);
    float* u1t  = alloc(160 * 64);
    float* fc1t = alloc(64 * 256);

    float* x1  = alloc((size_t)4 * 256 * 256 * 64);   // also x1o (in-place U1 out)
    float* x1d = alloc((size_t)4 * 128 * 128 * 64);   // reused as x2d
    float* x2  = alloc((size_t)4 * 128 * 128 * 96);
    float* xb  = alloc((size_t)4 * 64 * 64 * 128);
    float* x2o = alloc((size_t)4 * 128 * 128 * 96);

    float2* Fx = (float2*)alloc((size_t)2 * 4 * 256 * 12 * 160);
    float2* XF = (float2*)alloc((size_t)2 * 4 * 24 * 12 * 160);
    float2* OF = (float2*)alloc((size_t)2 * 4 * 24 * 12 * 128);
    float2* Gy = (float2*)alloc((size_t)2 * 4 * 256 * 12 * 96);

    size_t need = off * sizeof(float);
    if (ws_size < need) {
        fprintf(stderr, "[FNO2d] workspace too small: need %zu bytes, have %zu\n",
                need, ws_size);
        return;
    }
    float* x2d = x1d;

    init_tw_kernel<<<1, 256, 0, stream>>>(tw);
    transpose_mat_kernel<<<nb_(64 * 64, 256), 256, 0, stream>>>(c1_w, c1t, 64, 64);
    transpose_mat_kernel<<<nb_(64 * 96, 256), 256, 0, stream>>>(c2_w, c2t, 96, 64);
    transpose_mat_kernel<<<nb_(96 * 128, 256), 256, 0, stream>>>(cb_w, cbt, 128, 96);
    transpose_mat_kernel<<<nb_(224 * 96, 256), 256, 0, stream>>>(u2_w, u2t, 96, 224);
    transpose_mat_kernel<<<nb_(160 * 64, 256), 256, 0, stream>>>(u1_w, u1t, 64, 160);
    transpose_mat_kernel<<<nb_(64 * 256, 256), 256, 0, stream>>>(fc1_w, fc1t, 256, 64);

    int N;

    // ---- L1: lift(x) -> 64ch, 256x256, m=12, Co=64 -> x1
    dftx_kernel<12, 1, 256><<<dim3(256, 1), 256, 0, stream>>>(
        x, 64, 0, 64, 256, 0, 0, fcin_w, fcin_b, 1, tw, Fx);
    N = 4 * 24 * 12 * 64;
    dfty_kernel<<<nb_(N, 256), 256, 0, stream>>>(Fx, 256, 12, 12, 64, 1, tw, XF, N);
    modemix2_kernel<<<288, 128, 0, stream>>>(XF, sc1_w1, sc1_w2, 64, 64, 12, 12, OF);
    N = 4 * 256 * 12 * 64;
    idfty_kernel<<<nb_(N, 256), 256, 0, stream>>>(OF, 256, 12, 12, 64, 1, tw, Gy, N);
    synth_kernel<1, false, 64, 64, 12, 3><<<4 * 256 * 256 / 32, 128, 0, stream>>>(
        Gy, x, 64, 0, 0, nullptr, 0, fcin_w, fcin_b, c1t, c1_b,
        256, 256, 1, 1.0f / 65536.0f, tw, x1);
    N = 4 * 128 * 128 * 64;
    pool_kernel<<<nb_(N, 256), 256, 0, stream>>>(x1, x1d, 128, 128, 64, N);

    // ---- L2: x1d 64ch, 128x128, m=8, Co=96 -> x2
    dftx_kernel<8, 0, 128><<<dim3(128, 1), 256, 0, stream>>>(
        x1d, 64, 0, 64, 128, 0, 0, nullptr, nullptr, 2, tw, Fx);
    N = 4 * 16 * 8 * 64;
    dfty_kernel<<<nb_(N, 256), 256, 0, stream>>>(Fx, 128, 8, 8, 64, 2, tw, XF, N);
    modemix2_kernel<<<128, 128, 0, stream>>>(XF, sc2_w1, sc2_w2, 64, 96, 8, 8, OF);
    N = 4 * 128 * 8 * 96;
    idfty_kernel<<<nb_(N, 256), 256, 0, stream>>>(OF, 128, 8, 8, 96, 2, tw, Gy, N);
    synth_kernel<0, false, 96, 64, 8, 3><<<4 * 128 * 128 / 32, 192, 0, stream>>>(
        Gy, x1d, 64, 0, 0, nullptr, 0, nullptr, nullptr, c2t, c2_b,
        128, 128, 2, 1.0f / 16384.0f, tw, x2);
    N = 4 * 64 * 64 * 96;
    pool_kernel<<<nb_(N, 256), 256, 0, stream>>>(x2, x2d, 64, 64, 96, N);

    // ---- bottleneck: x2d 96ch, 64x64, m=4, Co=128 -> xb
    dftx_kernel<4, 0, 64><<<dim3(64, 2), 256, 0, stream>>>(
        x2d, 96, 0, 96, 64, 0, 0, nullptr, nullptr, 4, tw, Fx);
    N = 4 * 8 * 4 * 96;
    dfty_kernel<<<nb_(N, 256), 256, 0, stream>>>(Fx, 64, 4, 4, 96, 4, tw, XF, N);
    modemix2_kernel<<<32, 128, 0, stream>>>(XF, scb_w1, scb_w2, 96, 128, 4, 4, OF);
    N = 4 * 64 * 4 * 128;
    idfty_kernel<<<nb_(N, 256), 256, 0, stream>>>(OF, 64, 4, 4, 128, 4, tw, Gy, N);
    synth_kernel<0, false, 128, 96, 4, 2><<<4 * 64 * 64 / 32, 256, 0, stream>>>(
        Gy, x2d, 96, 0, 0, nullptr, 0, nullptr, nullptr, cbt, cb_b,
        64, 64, 4, 1.0f / 4096.0f, tw, xb);

    // ---- U2: [up(xb) 128ch | x2 96ch], 128x128, m=8, Co=96 -> x2o
    dftx_kernel<8, 2, 128><<<dim3(128, 2), 256, 0, stream>>>(
        xb, 128, 0, 224, 128, 64, 64, nullptr, nullptr, 2, tw, Fx);
    dftx_kernel<8, 0, 128><<<dim3(128, 2), 256, 0, stream>>>(
        x2, 96, 128, 224, 128, 0, 0, nullptr, nullptr, 2, tw, Fx);
    N = 4 * 16 * 8 * 224;
    dfty_kernel<<<nb_(N, 256), 256, 0, stream>>>(Fx, 128, 8, 8, 224, 2, tw, XF, N);
    modemix2_kernel<<<128, 128, 0, stream>>>(XF, su2_w1, su2_w2, 224, 96, 8, 8, OF);
    N = 4 * 128 * 8 * 96;
    idfty_kernel<<<nb_(N, 256), 256, 0, stream>>>(OF, 128, 8, 8, 96, 2, tw, Gy, N);
    synth_kernel<2, true, 96, 224, 8, 2><<<4 * 128 * 128 / 32, 192, 0, stream>>>(
        Gy, xb, 128, 64, 64, x2, 96, nullptr, nullptr, u2t, u2_b,
        128, 128, 2, 1.0f / 16384.0f, tw, x2o);

    // ---- U1: [up(x2o) 96ch | x1 64ch], 256x256, m=12, Co=64 -> x1 (in-place)
    dftx_kernel<12, 2, 256><<<dim3(256, 2), 256, 0, stream>>>(
        x2o, 96, 0, 160, 256, 128, 128, nullptr, nullptr, 1, tw, Fx);
    dftx_kernel<12, 0, 256><<<dim3(256, 1), 256, 0, stream>>>(
        x1, 64, 96, 160, 256, 0, 0, nullptr, nullptr, 1, tw, Fx);
    N = 4 * 24 * 12 * 160;
    dfty_kernel<<<nb_(N, 256), 256, 0, stream>>>(Fx, 256, 12, 12, 160, 1, tw, XF, N);
    modemix2_kernel<<<288, 128, 0, stream>>>(XF, su1_w1, su1_w2, 160, 64, 12, 12, OF);
    N = 4 * 256 * 12 * 64;
    idfty_kernel<<<nb_(N, 256), 256, 0, stream>>>(OF, 256, 12, 12, 64, 1, tw, Gy, N);
    // writes x1 in place: each block reads/writes only its own pixel rows of x1
    synth_kernel<2, true, 64, 160, 12, 3><<<4 * 256 * 256 / 32, 128, 0, stream>>>(
        Gy, x2o, 96, 128, 128, x1, 64, nullptr, nullptr, u1t, u1_b,
        256, 256, 1, 1.0f / 65536.0f, tw, x1);

    // ---- head: fc2(gelu(fc1(x1o)))
    head_kernel<<<4 * 256 * 256 / 16, 256, 0, stream>>>(
        x1, fc1t, fc1_b, fc2_w, fc2_b, out);
}